// Round 8
// baseline (216.634 us; speedup 1.0000x reference)
//
#include <hip/hip_runtime.h>
#include <cstdint>

typedef unsigned short u16;
typedef __attribute__((ext_vector_type(8))) short short8;
typedef __attribute__((ext_vector_type(4))) float f32x4;

#if __has_builtin(__builtin_amdgcn_exp2f)
#define EXP2F(x) __builtin_amdgcn_exp2f(x)
#else
#define EXP2F(x) exp2f(x)
#endif

// fp32 -> bf16 bits, round-to-nearest-even
__device__ inline u16 f2bf(float f) {
  union { float f; unsigned u; } v; v.f = f;
  unsigned u = v.u;
  return (u16)((u + 0x7fffu + ((u >> 16) & 1u)) >> 16);
}

// pack two fp32 -> bf16x2 (a -> low); round-half-up (P>0 only, 1ulp vs RNE)
__device__ inline unsigned pk2bf_fast(float a, float b) {
  union { float f; unsigned u; } ua, ub; ua.f = a; ub.f = b;
  return __builtin_amdgcn_perm(ub.u + 0x8000u, ua.u + 0x8000u, 0x07060302u);
}

// async global -> LDS, 16B per lane (contiguous landing order only)
__device__ inline void gl2lds16(const void* g, void* l) {
  __builtin_amdgcn_global_load_lds(
      (const __attribute__((address_space(1))) unsigned int*)(unsigned long long)(uintptr_t)g,
      (__attribute__((address_space(3))) unsigned int*)(unsigned int)(uintptr_t)l,
      16, 0, 0);
}

// XOR chunk swizzle: within each 64-elem K-slice of a row, 16B chunk c of row
// r is stored at position c ^ (r & 7). gl2lds staging copies slices verbatim;
// fragment reads at chunk' = (kk*4+lg) ^ (l15&7) are phase-conflict-free.

// ---------------------------------------------------------------- cvt kernel
__global__ __launch_bounds__(256) void cvt_kernel(
    const float* __restrict__ x,
    const float* __restrict__ wq, const float* __restrict__ wk,
    const float* __restrict__ wv, const float* __restrict__ wo,
    u16* __restrict__ xb, u16* __restrict__ wqb, u16* __restrict__ wkb,
    u16* __restrict__ wvb, u16* __restrict__ wob) {
  const int y = blockIdx.y;
  const int Q = 1 << 20;
  const float* src;
  u16* dst;
  if (y < 4)       { src = x + y * Q; dst = xb + y * Q; }
  else if (y == 4) { src = wq; dst = wqb; }
  else if (y == 5) { src = wk; dst = wkb; }
  else if (y == 6) { src = wv; dst = wvb; }
  else             { src = wo; dst = wob; }
  const int i = (blockIdx.x * 256 + threadIdx.x) * 8;
  float4 a = *(const float4*)(src + i);
  float4 b = *(const float4*)(src + i + 4);
  short8 o;
  o[0] = (short)f2bf(a.x); o[1] = (short)f2bf(a.y);
  o[2] = (short)f2bf(a.z); o[3] = (short)f2bf(a.w);
  o[4] = (short)f2bf(b.x); o[5] = (short)f2bf(b.y);
  o[6] = (short)f2bf(b.z); o[7] = (short)f2bf(b.w);
  const int j = (i & ~63) | (((((i >> 3) & 7) ^ ((i >> 10) & 7))) << 3);
  *(short8*)(dst + j) = o;
}

// ------------------------------------------------------------ QKV projection
// NT GEMM, M=4096 N=1024 K=1024; 128m x 64n tiles, grid (16, 32, 3) = 1536
// blocks, 48 KB LDS -> 3 blocks/CU (12 waves), exactly 2 rounds.
// Double-buffered gl2lds, one barrier per K-iter.
// z==0 -> Q plain [B,NH,S,D]; z==1 -> K chunk-swizzled by s&7;
// z==2 -> V^T [B,NH,D,Sperm] (sigma(s)=(s&15)*4+(s>>4)&3), swizzled by d&7.
__global__ __launch_bounds__(256) void gemm_qkv(
    const u16* __restrict__ xb,
    const u16* __restrict__ wqb, const u16* __restrict__ wkb, const u16* __restrict__ wvb,
    const float* __restrict__ bq, const float* __restrict__ bk, const float* __restrict__ bv,
    u16* __restrict__ qo, u16* __restrict__ ko, u16* __restrict__ vto) {
  const int z = blockIdx.z;
  const u16* W = (z == 0) ? wqb : (z == 1) ? wkb : wvb;
  const float* bias = (z == 0) ? bq : (z == 1) ? bk : bv;

  __shared__ u16 smem[24576];        // As[2][8192] | Bs[2][4096] = 48 KB
  u16* As = smem;
  u16* Bs = smem + 16384;
  const int tid = threadIdx.x, lane = tid & 63;
  const int wid = tid >> 6;
  const int l15 = lane & 15, lg = lane >> 4;
  const int m0 = blockIdx.y * 128, n0 = blockIdx.x * 64;
  const int sw = ((l15 & 7) << 3);

  f32x4 acc[2][4] = {};

  // prologue: stage k0=0 into buffer 0
#pragma unroll
  for (int i = 0; i < 4; ++i) {
    int c = i * 256 + tid;
    gl2lds16(xb + (m0 + (c >> 3)) * 1024 + (c & 7) * 8, As + c * 8);
  }
#pragma unroll
  for (int i = 0; i < 2; ++i) {
    int c = i * 256 + tid;
    gl2lds16(W + (n0 + (c >> 3)) * 1024 + (c & 7) * 8, Bs + c * 8);
  }

  for (int k0 = 0; k0 < 1024; k0 += 64) {
    const int p = (k0 >> 6) & 1;
    __syncthreads();  // drains vmcnt -> buf p ready
    if (k0 < 960) {
      u16* An = As + (1 - p) * 8192;
      u16* Bn = Bs + (1 - p) * 4096;
#pragma unroll
      for (int i = 0; i < 4; ++i) {
        int c = i * 256 + tid;
        gl2lds16(xb + (m0 + (c >> 3)) * 1024 + k0 + 64 + (c & 7) * 8, An + c * 8);
      }
#pragma unroll
      for (int i = 0; i < 2; ++i) {
        int c = i * 256 + tid;
        gl2lds16(W + (n0 + (c >> 3)) * 1024 + k0 + 64 + (c & 7) * 8, Bn + c * 8);
      }
    }
    const u16* Ap = As + p * 8192;
    const u16* Bp = Bs + p * 4096;
#pragma unroll
    for (int kk = 0; kk < 2; ++kk) {
      short8 af[2], bf[4];
#pragma unroll
      for (int mb = 0; mb < 2; ++mb)
        af[mb] = *(const short8*)(Ap + (wid * 32 + mb * 16 + l15) * 64 + ((((kk * 4 + lg) << 3)) ^ sw));
#pragma unroll
      for (int nb = 0; nb < 4; ++nb)
        bf[nb] = *(const short8*)(Bp + (nb * 16 + l15) * 64 + ((((kk * 4 + lg) << 3)) ^ sw));
#pragma unroll
      for (int mb = 0; mb < 2; ++mb)
#pragma unroll
        for (int nb = 0; nb < 4; ++nb)
          acc[mb][nb] = __builtin_amdgcn_mfma_f32_16x16x32_bf16(af[mb], bf[nb], acc[mb][nb], 0, 0, 0);
    }
  }

  if (z < 2) {
    u16* out = (z == 0) ? qo : ko;
#pragma unroll
    for (int mb = 0; mb < 2; ++mb)
#pragma unroll
      for (int nb = 0; nb < 4; ++nb)
#pragma unroll
        for (int r = 0; r < 4; ++r) {
          int m = m0 + wid * 32 + mb * 16 + lg * 4 + r;  // b*2048 + s
          int n = n0 + nb * 16 + l15;                    // h*64 + d
          float v = acc[mb][nb][r] + bias[n];
          int b = m >> 11, s = m & 2047, hh = n >> 6, d = n & 63;
          int dcol = (z == 0) ? d : ((((d >> 3) ^ (s & 7)) << 3) | (d & 7));
          out[((b * 16 + hh) * 2048 + s) * 64 + dcol] = f2bf(v);
        }
  } else {
    // V^T epilogue: two shared 64(d) x 72 transpose buffers (wave-pairs
    // share one 64-key s-block each), then coalesced 16B global stores.
    __syncthreads();  // all waves done with As/Bs
    u16* wbuf = smem + (wid >> 1) * 4608;
    const int so = (wid & 1) * 2;
#pragma unroll
    for (int mb = 0; mb < 2; ++mb)
#pragma unroll
      for (int nb = 0; nb < 4; ++nb) {
        int n = n0 + nb * 16 + l15;
        float bn = bias[n];
        int dl = nb * 16 + l15;
#pragma unroll
        for (int r = 0; r < 4; ++r) {
          int sig = (lg * 4 + r) * 4 + so + mb;  // sigma of s within 64-block
          wbuf[dl * 72 + sig] = f2bf(acc[mb][nb][r] + bn);
        }
      }
    __syncthreads();  // cross-wave transpose complete
    int hh = n0 >> 6;
    int bb = m0 >> 11;
    int sbase = m0 & 2047;
#pragma unroll
    for (int i = 0; i < 4; ++i) {
      int idx = i * 256 + tid;           // 1024 chunks = 2 bufs x 64 x 8
      int p2 = idx >> 9, rem = idx & 511;
      int dl = rem >> 3, c = rem & 7;
      short8 vv = *(const short8*)(smem + p2 * 4608 + dl * 72 + c * 8);
      int cs = c ^ (dl & 7);             // chunk swizzle by d&7
      *(short8*)(vto + ((bb * 16 + hh) * 64 + dl) * 2048 + sbase + p2 * 64 + cs * 8) = vv;
    }
  }
}

// ---------------------------------------------------------------- attention
// flash-style, Q-tile 128 x K-tile 64, grid (16,16,2), 128 threads (2 waves
// of 64 q-rows -> 2x MFMA per LDS fragment read vs 4x32). K/V^T staged via
// gl2lds double-buffer, one barrier per kt. Fragment reads conflict-free via
// baked chunk swizzle. Q fragments direct from global (once). Fixed-max
// softmax P = exp2(s*log2e/8 - 4); row-sum via ones-register B operand.
__global__ __launch_bounds__(128, 2) void attn_kernel(
    const u16* __restrict__ qg, const u16* __restrict__ kg,
    const u16* __restrict__ vtg, u16* __restrict__ ctxg) {
  const int h = blockIdx.x, qt = blockIdx.y, b = blockIdx.z;
  const int bh = b * 16 + h;
  const u16* Qg = qg + (bh * 2048 + qt * 128) * 64;
  const u16* Kg = kg + bh * 2048 * 64;
  const u16* Vg = vtg + bh * 64 * 2048;

  __shared__ u16 SP[128 * 72];   // P round-trip; wave-private 64-row strips
  __shared__ u16 KV[2][8192];    // [p][0:4096)=K tile, [p][4096:8192)=V^T

  const int tid = threadIdx.x, lane = tid & 63, wid = tid >> 6;
  const int l15 = lane & 15, lg = lane >> 4;
  const int row0 = wid * 64;
  const int sw = ((l15 & 7) << 3);

  // Q fragments direct from global (plain layout, reused all 32 kt)
  short8 qf[4][2];
#pragma unroll
  for (int mb = 0; mb < 4; ++mb)
#pragma unroll
    for (int kk = 0; kk < 2; ++kk)
      qf[mb][kk] = *(const short8*)(Qg + (row0 + mb * 16 + l15) * 64 + kk * 32 + lg * 8);

  short8 ones8;
#pragma unroll
  for (int j = 0; j < 8; ++j) ones8[j] = (short)0x3F80;  // bf16 1.0

  // prologue: stage kt=0 into buffer 0 (128 threads -> 4 iters each)
#pragma unroll
  for (int i = 0; i < 4; ++i) {
    int c = i * 128 + tid;
    gl2lds16(Kg + c * 8, &KV[0][c * 8]);
    gl2lds16(Vg + (c >> 3) * 2048 + (c & 7) * 8, &KV[0][4096 + c * 8]);
  }

  f32x4 acc[4][5] = {};  // nd 0..3 = ctx, nd 4 = row-sum
  const float cexp = 0.18033688011112042f;  // log2(e)/8

  for (int kt = 0; kt < 32; ++kt) {
    const int p = kt & 1;
    __syncthreads();  // drains vmcnt -> buf p ready
    if (kt < 31) {
#pragma unroll
      for (int i = 0; i < 4; ++i) {
        int c = i * 128 + tid;
        gl2lds16(Kg + (kt + 1) * 4096 + c * 8, &KV[1 - p][c * 8]);
        gl2lds16(Vg + (c >> 3) * 2048 + (kt + 1) * 64 + (c & 7) * 8, &KV[1 - p][4096 + c * 8]);
      }
    }
    const u16* Ks = &KV[p][0];
    const u16* Vts = &KV[p][4096];

    // S = Q K^T
    f32x4 sc[4][4] = {};
#pragma unroll
    for (int kk = 0; kk < 2; ++kk) {
      short8 bfr[4];
#pragma unroll
      for (int nb = 0; nb < 4; ++nb)
        bfr[nb] = *(const short8*)(Ks + (nb * 16 + l15) * 64 + ((((kk * 4 + lg) << 3)) ^ sw));
#pragma unroll
      for (int mb = 0; mb < 4; ++mb)
#pragma unroll
        for (int nb = 0; nb < 4; ++nb)
          sc[mb][nb] = __builtin_amdgcn_mfma_f32_16x16x32_bf16(qf[mb][kk], bfr[nb], sc[mb][nb], 0, 0, 0);
    }

    // P = exp2(s*c - 4); sigma(key = nb*16+l15) = l15*4+nb -> b64 per row
#pragma unroll
    for (int mb = 0; mb < 4; ++mb)
#pragma unroll
      for (int r = 0; r < 4; ++r) {
        float p0 = EXP2F(fmaf(sc[mb][0][r], cexp, -4.0f));
        float p1 = EXP2F(fmaf(sc[mb][1][r], cexp, -4.0f));
        float p2 = EXP2F(fmaf(sc[mb][2][r], cexp, -4.0f));
        float p3 = EXP2F(fmaf(sc[mb][3][r], cexp, -4.0f));
        uint2 u;
        u.x = pk2bf_fast(p0, p1);
        u.y = pk2bf_fast(p2, p3);
        *(uint2*)(SP + (row0 + mb * 16 + lg * 4 + r) * 72 + l15 * 4) = u;
      }

    // ctx += P @ [V | 1]  (same-wave LDS write->read, in-order)
#pragma unroll
    for (int kk = 0; kk < 2; ++kk) {
      short8 pa[4], vb[4];
#pragma unroll
      for (int mb = 0; mb < 4; ++mb)
        pa[mb] = *(const short8*)(SP + (row0 + mb * 16 + l15) * 72 + kk * 32 + lg * 8);
#pragma unroll
      for (int nd = 0; nd < 4; ++nd)
        vb[nd] = *(const short8*)(Vts + (nd * 16 + l15) * 64 + ((((kk * 4 + lg) << 3)) ^ sw));
#pragma unroll
      for (int mb = 0; mb < 4; ++mb) {
#pragma unroll
        for (int nd = 0; nd < 4; ++nd)
          acc[mb][nd] = __builtin_amdgcn_mfma_f32_16x16x32_bf16(pa[mb], vb[nd], acc[mb][nd], 0, 0, 0);
        acc[mb][4] = __builtin_amdgcn_mfma_f32_16x16x32_bf16(pa[mb], ones8, acc[mb][4], 0, 0, 0);
      }
    }
  }

  // epilogue: l = acc[mb][4][r] (replicated across cols); ctx stored
  // chunk-swizzled by s&7 for gemm_out's fragment reads.
#pragma unroll
  for (int mb = 0; mb < 4; ++mb)
#pragma unroll
    for (int r = 0; r < 4; ++r) {
      float inv = 1.0f / acc[mb][4][r];
      int s = qt * 128 + row0 + mb * 16 + lg * 4 + r;
      int s7 = s & 7;
      u16* dst = ctxg + (b * 2048 + s) * 1024 + h * 64;
#pragma unroll
      for (int nd = 0; nd < 4; ++nd) {
        int d = nd * 16 + l15;
        int dcol = (((d >> 3) ^ s7) << 3) | (d & 7);
        dst[dcol] = f2bf(acc[mb][nd][r] * inv);
      }
    }
}

// ------------------------------------------------------------ out projection
// out[m,n] = sum_k ctx[m,k]*Wo[n,k] + bo[n], fp32 out. 64x64 tiles, grid
// (16,64) = 1024 blocks, 32 KB LDS -> exactly 4 blocks/CU (16 waves).
__global__ __launch_bounds__(256) void gemm_out(
    const u16* __restrict__ cb, const u16* __restrict__ wob,
    const float* __restrict__ bo, float* __restrict__ out) {
  __shared__ u16 smem[16384];  // As[2][4096] | Bs[2][4096] = 32 KB
  u16* As = smem;
  u16* Bs = smem + 8192;
  const int tid = threadIdx.x, lane = tid & 63;
  const int wid = tid >> 6;
  const int l15 = lane & 15, lg = lane >> 4;
  const int m0 = blockIdx.y * 64, n0 = blockIdx.x * 64;
  const int sw = ((l15 & 7) << 3);

  f32x4 acc[4] = {};

#pragma unroll
  for (int i = 0; i < 2; ++i) {
    int c = i * 256 + tid;
    gl2lds16(cb  + (m0 + (c >> 3)) * 1024 + (c & 7) * 8, As + c * 8);
    gl2lds16(wob + (n0 + (c >> 3)) * 1024 + (c & 7) * 8, Bs + c * 8);
  }

  for (int k0 = 0; k0 < 1024; k0 += 64) {
    const int p = (k0 >> 6) & 1;
    __syncthreads();
    if (k0 < 960) {
      u16* An = As + (1 - p) * 4096;
      u16* Bn = Bs + (1 - p) * 4096;
#pragma unroll
      for (int i = 0; i < 2; ++i) {
        int c = i * 256 + tid;
        gl2lds16(cb  + (m0 + (c >> 3)) * 1024 + k0 + 64 + (c & 7) * 8, An + c * 8);
        gl2lds16(wob + (n0 + (c >> 3)) * 1024 + k0 + 64 + (c & 7) * 8, Bn + c * 8);
      }
    }
    const u16* Ap = As + p * 4096;
    const u16* Bp = Bs + p * 4096;
#pragma unroll
    for (int kk = 0; kk < 2; ++kk) {
      short8 af, bf[4];
      af = *(const short8*)(Ap + (wid * 16 + l15) * 64 + ((((kk * 4 + lg) << 3)) ^ sw));
#pragma unroll
      for (int nb = 0; nb < 4; ++nb)
        bf[nb] = *(const short8*)(Bp + (nb * 16 + l15) * 64 + ((((kk * 4 + lg) << 3)) ^ sw));
#pragma unroll
      for (int nb = 0; nb < 4; ++nb)
        acc[nb] = __builtin_amdgcn_mfma_f32_16x16x32_bf16(af, bf[nb], acc[nb], 0, 0, 0);
    }
  }

#pragma unroll
  for (int nb = 0; nb < 4; ++nb)
#pragma unroll
    for (int r = 0; r < 4; ++r) {
      int m = m0 + wid * 16 + lg * 4 + r;
      int n = n0 + nb * 16 + l15;
      out[m * 1024 + n] = acc[nb][r] + bo[n];
    }
}

// --------------------------------------------------------------------- launch
extern "C" void kernel_launch(void* const* d_in, const int* in_sizes, int n_in,
                              void* d_out, int out_size, void* d_ws, size_t ws_size,
                              hipStream_t stream) {
  const float* x  = (const float*)d_in[0];
  const float* wq = (const float*)d_in[1];
  const float* bq = (const float*)d_in[2];
  const float* wk = (const float*)d_in[3];
  const float* bk = (const float*)d_in[4];
  const float* wv = (const float*)d_in[5];
  const float* bv = (const float*)d_in[6];
  const float* wo = (const float*)d_in[7];
  const float* bo = (const float*)d_in[8];

  if (ws_size < (size_t)24 * 1024 * 1024 * 2) return;
  u16* xb   = (u16*)d_ws;              // chunk-swizzled
  u16* wqb  = xb  + (4u << 20);        // chunk-swizzled
  u16* wkb  = wqb + (1u << 20);
  u16* wvb  = wkb + (1u << 20);
  u16* wob  = wvb + (1u << 20);
  u16* qb   = wob + (1u << 20);        // plain [B,NH,S,D]
  u16* kb   = qb  + (4u << 20);        // chunk-swizzled [B,NH,S,D]
  u16* vtb  = kb  + (4u << 20);        // V^T [B,NH,D,Sperm], chunk-swizzled
  u16* ctxb = vtb + (4u << 20);        // chunk-swizzled [B,S,H]

  cvt_kernel<<<dim3(512, 8, 1), 256, 0, stream>>>(x, wq, wk, wv, wo, xb, wqb, wkb, wvb, wob);
  gemm_qkv<<<dim3(16, 32, 3), 256, 0, stream>>>(xb, wqb, wkb, wvb, bq, bk, bv, qb, kb, vtb);
  attn_kernel<<<dim3(16, 16, 2), 128, 0, stream>>>(qb, kb, vtb, ctxb);
  gemm_out<<<dim3(16, 64, 1), 256, 0, stream>>>(ctxb, wob, bo, (float*)d_out);
}

// Round 9
// 202.688 us; speedup vs baseline: 1.0688x; 1.0688x over previous
//
#include <hip/hip_runtime.h>
#include <cstdint>

typedef unsigned short u16;
typedef __attribute__((ext_vector_type(8))) short short8;
typedef __attribute__((ext_vector_type(4))) float f32x4;

#if __has_builtin(__builtin_amdgcn_exp2f)
#define EXP2F(x) __builtin_amdgcn_exp2f(x)
#else
#define EXP2F(x) exp2f(x)
#endif

// fp32 -> bf16 bits, round-to-nearest-even
__device__ inline u16 f2bf(float f) {
  union { float f; unsigned u; } v; v.f = f;
  unsigned u = v.u;
  return (u16)((u + 0x7fffu + ((u >> 16) & 1u)) >> 16);
}

// pack two fp32 -> bf16x2 (a -> low); round-half-up (P>0 only, 1ulp vs RNE)
__device__ inline unsigned pk2bf_fast(float a, float b) {
  union { float f; unsigned u; } ua, ub; ua.f = a; ub.f = b;
  return __builtin_amdgcn_perm(ub.u + 0x8000u, ua.u + 0x8000u, 0x07060302u);
}

// async global -> LDS, 16B per lane (contiguous landing order only)
__device__ inline void gl2lds16(const void* g, void* l) {
  __builtin_amdgcn_global_load_lds(
      (const __attribute__((address_space(1))) unsigned int*)(unsigned long long)(uintptr_t)g,
      (__attribute__((address_space(3))) unsigned int*)(unsigned int)(uintptr_t)l,
      16, 0, 0);
}

// XOR chunk swizzle: within each 64-elem K-slice of a row, 16B chunk c of row
// r is stored at position c ^ (r & 7). gl2lds staging copies slices verbatim;
// fragment reads at chunk' = (kk*4+lg) ^ (l15&7) are phase-conflict-free.

// ---------------------------------------------------------------- cvt kernel
__global__ __launch_bounds__(256) void cvt_kernel(
    const float* __restrict__ x,
    const float* __restrict__ wq, const float* __restrict__ wk,
    const float* __restrict__ wv, const float* __restrict__ wo,
    u16* __restrict__ xb, u16* __restrict__ wqb, u16* __restrict__ wkb,
    u16* __restrict__ wvb, u16* __restrict__ wob) {
  const int y = blockIdx.y;
  const int Q = 1 << 20;
  const float* src;
  u16* dst;
  if (y < 4)       { src = x + y * Q; dst = xb + y * Q; }
  else if (y == 4) { src = wq; dst = wqb; }
  else if (y == 5) { src = wk; dst = wkb; }
  else if (y == 6) { src = wv; dst = wvb; }
  else             { src = wo; dst = wob; }
  const int i = (blockIdx.x * 256 + threadIdx.x) * 8;
  float4 a = *(const float4*)(src + i);
  float4 b = *(const float4*)(src + i + 4);
  short8 o;
  o[0] = (short)f2bf(a.x); o[1] = (short)f2bf(a.y);
  o[2] = (short)f2bf(a.z); o[3] = (short)f2bf(a.w);
  o[4] = (short)f2bf(b.x); o[5] = (short)f2bf(b.y);
  o[6] = (short)f2bf(b.z); o[7] = (short)f2bf(b.w);
  const int j = (i & ~63) | (((((i >> 3) & 7) ^ ((i >> 10) & 7))) << 3);
  *(short8*)(dst + j) = o;
}

// ------------------------------------------------------------ QKV projection
// NT GEMM, M=4096 N=1024 K=1024; 128m x 64n tiles, grid (16, 32, 3) = 1536
// blocks, 48 KB LDS -> 3 blocks/CU, exactly 2 rounds. Double-buffered gl2lds,
// one barrier per K-iter.
// z==0 -> Q plain [B,NH,S,D]; z==1 -> K plain [B,NH,S,D] (attn reads K frags
// directly from global); z==2 -> V^T [B,NH,D,Sperm]
// (sigma(s)=(s&15)*4+(s>>4)&3), chunk-swizzled by d&7.
__global__ __launch_bounds__(256) void gemm_qkv(
    const u16* __restrict__ xb,
    const u16* __restrict__ wqb, const u16* __restrict__ wkb, const u16* __restrict__ wvb,
    const float* __restrict__ bq, const float* __restrict__ bk, const float* __restrict__ bv,
    u16* __restrict__ qo, u16* __restrict__ ko, u16* __restrict__ vto) {
  const int z = blockIdx.z;
  const u16* W = (z == 0) ? wqb : (z == 1) ? wkb : wvb;
  const float* bias = (z == 0) ? bq : (z == 1) ? bk : bv;

  __shared__ u16 smem[24576];        // As[2][8192] | Bs[2][4096] = 48 KB
  u16* As = smem;
  u16* Bs = smem + 16384;
  const int tid = threadIdx.x, lane = tid & 63;
  const int wid = tid >> 6;
  const int l15 = lane & 15, lg = lane >> 4;
  const int m0 = blockIdx.y * 128, n0 = blockIdx.x * 64;
  const int sw = ((l15 & 7) << 3);

  f32x4 acc[2][4] = {};

  // prologue: stage k0=0 into buffer 0
#pragma unroll
  for (int i = 0; i < 4; ++i) {
    int c = i * 256 + tid;
    gl2lds16(xb + (m0 + (c >> 3)) * 1024 + (c & 7) * 8, As + c * 8);
  }
#pragma unroll
  for (int i = 0; i < 2; ++i) {
    int c = i * 256 + tid;
    gl2lds16(W + (n0 + (c >> 3)) * 1024 + (c & 7) * 8, Bs + c * 8);
  }

  for (int k0 = 0; k0 < 1024; k0 += 64) {
    const int p = (k0 >> 6) & 1;
    __syncthreads();  // drains vmcnt -> buf p ready
    if (k0 < 960) {
      u16* An = As + (1 - p) * 8192;
      u16* Bn = Bs + (1 - p) * 4096;
#pragma unroll
      for (int i = 0; i < 4; ++i) {
        int c = i * 256 + tid;
        gl2lds16(xb + (m0 + (c >> 3)) * 1024 + k0 + 64 + (c & 7) * 8, An + c * 8);
      }
#pragma unroll
      for (int i = 0; i < 2; ++i) {
        int c = i * 256 + tid;
        gl2lds16(W + (n0 + (c >> 3)) * 1024 + k0 + 64 + (c & 7) * 8, Bn + c * 8);
      }
    }
    const u16* Ap = As + p * 8192;
    const u16* Bp = Bs + p * 4096;
#pragma unroll
    for (int kk = 0; kk < 2; ++kk) {
      short8 af[2], bf[4];
#pragma unroll
      for (int mb = 0; mb < 2; ++mb)
        af[mb] = *(const short8*)(Ap + (wid * 32 + mb * 16 + l15) * 64 + ((((kk * 4 + lg) << 3)) ^ sw));
#pragma unroll
      for (int nb = 0; nb < 4; ++nb)
        bf[nb] = *(const short8*)(Bp + (nb * 16 + l15) * 64 + ((((kk * 4 + lg) << 3)) ^ sw));
#pragma unroll
      for (int mb = 0; mb < 2; ++mb)
#pragma unroll
        for (int nb = 0; nb < 4; ++nb)
          acc[mb][nb] = __builtin_amdgcn_mfma_f32_16x16x32_bf16(af[mb], bf[nb], acc[mb][nb], 0, 0, 0);
    }
  }

  if (z < 2) {
    u16* out = (z == 0) ? qo : ko;
#pragma unroll
    for (int mb = 0; mb < 2; ++mb)
#pragma unroll
      for (int nb = 0; nb < 4; ++nb)
#pragma unroll
        for (int r = 0; r < 4; ++r) {
          int m = m0 + wid * 32 + mb * 16 + lg * 4 + r;  // b*2048 + s
          int n = n0 + nb * 16 + l15;                    // h*64 + d
          float v = acc[mb][nb][r] + bias[n];
          int b = m >> 11, s = m & 2047, hh = n >> 6, d = n & 63;
          out[((b * 16 + hh) * 2048 + s) * 64 + d] = f2bf(v);
        }
  } else {
    // V^T epilogue: two shared 64(d) x 72 transpose buffers (wave-pairs
    // share one 64-key s-block each), then coalesced 16B global stores.
    __syncthreads();  // all waves done with As/Bs
    u16* wbuf = smem + (wid >> 1) * 4608;
    const int so = (wid & 1) * 2;
#pragma unroll
    for (int mb = 0; mb < 2; ++mb)
#pragma unroll
      for (int nb = 0; nb < 4; ++nb) {
        int n = n0 + nb * 16 + l15;
        float bn = bias[n];
        int dl = nb * 16 + l15;
#pragma unroll
        for (int r = 0; r < 4; ++r) {
          int sig = (lg * 4 + r) * 4 + so + mb;  // sigma of s within 64-block
          wbuf[dl * 72 + sig] = f2bf(acc[mb][nb][r] + bn);
        }
      }
    __syncthreads();  // cross-wave transpose complete
    int hh = n0 >> 6;
    int bb = m0 >> 11;
    int sbase = m0 & 2047;
#pragma unroll
    for (int i = 0; i < 4; ++i) {
      int idx = i * 256 + tid;           // 1024 chunks = 2 bufs x 64 x 8
      int p2 = idx >> 9, rem = idx & 511;
      int dl = rem >> 3, c = rem & 7;
      short8 vv = *(const short8*)(smem + p2 * 4608 + dl * 72 + c * 8);
      int cs = c ^ (dl & 7);             // chunk swizzle by d&7
      *(short8*)(vto + ((bb * 16 + hh) * 64 + dl) * 2048 + sbase + p2 * 64 + cs * 8) = vv;
    }
  }
}

// ---------------------------------------------------------------- attention
// flash-style, Q-tile 128 x K-tile 64, grid (16,16,2), 256 thr (4 waves x 32
// q-rows). K fragments come DIRECTLY from global registers, software-
// pipelined one kt ahead (issued after softmax, covered by PV+barrier+
// V-staging) -> no ds_read K at the head of the per-kt chain. V^T staged via
// gl2lds double-buffer (chunk-swizzled reads). Fixed-max softmax
// P = exp2(s*log2e/8 - 4); row-sum via ones-register B operand.
__global__ __launch_bounds__(256, 2) void attn_kernel(
    const u16* __restrict__ qg, const u16* __restrict__ kg,
    const u16* __restrict__ vtg, u16* __restrict__ ctxg) {
  const int h = blockIdx.x, qt = blockIdx.y, b = blockIdx.z;
  const int bh = b * 16 + h;
  const u16* Qg = qg + (bh * 2048 + qt * 128) * 64;
  const u16* Kg = kg + bh * 2048 * 64;
  const u16* Vg = vtg + bh * 64 * 2048;

  __shared__ u16 SP[128 * 72];   // P round-trip; wave-private 32-row strips
  __shared__ u16 Vs[2][4096];    // V^T tile double buffer (16 KB)

  const int tid = threadIdx.x, lane = tid & 63, wid = tid >> 6;
  const int l15 = lane & 15, lg = lane >> 4;
  const int row0 = wid * 32;
  const int sw = ((l15 & 7) << 3);

  // Q fragments direct from global (plain layout, reused all 32 kt)
  short8 qf[2][2];
#pragma unroll
  for (int mb = 0; mb < 2; ++mb)
#pragma unroll
    for (int kk = 0; kk < 2; ++kk)
      qf[mb][kk] = *(const short8*)(Qg + (row0 + mb * 16 + l15) * 64 + kk * 32 + lg * 8);

  short8 ones8;
#pragma unroll
  for (int j = 0; j < 8; ++j) ones8[j] = (short)0x3F80;  // bf16 1.0

  // K fragment base (plain layout): + kt*4096 + nb*1024 + kk*32
  const u16* kbase = Kg + l15 * 64 + lg * 8;

  // preload kt=0 K fragments into registers
  short8 kf[2][4];
#pragma unroll
  for (int kk = 0; kk < 2; ++kk)
#pragma unroll
    for (int nb = 0; nb < 4; ++nb)
      kf[kk][nb] = *(const short8*)(kbase + nb * 1024 + kk * 32);

  // stage V kt=0 into buffer 0
#pragma unroll
  for (int i = 0; i < 2; ++i) {
    int c = i * 256 + tid;
    gl2lds16(Vg + (c >> 3) * 2048 + (c & 7) * 8, &Vs[0][c * 8]);
  }

  f32x4 acc[2][5] = {};  // nd 0..3 = ctx, nd 4 = row-sum
  const float cexp = 0.18033688011112042f;  // log2(e)/8

  for (int kt = 0; kt < 32; ++kt) {
    const int p = kt & 1;
    __syncthreads();  // drains vmcnt -> V buf p ready (K regs already drained)
    if (kt < 31) {
#pragma unroll
      for (int i = 0; i < 2; ++i) {
        int c = i * 256 + tid;
        gl2lds16(Vg + (c >> 3) * 2048 + (kt + 1) * 64 + (c & 7) * 8, &Vs[1 - p][c * 8]);
      }
    }
    const u16* Vts = &Vs[p][0];

    // S = Q K^T — from registers, issues immediately after the barrier
    f32x4 sc[2][4] = {};
#pragma unroll
    for (int kk = 0; kk < 2; ++kk)
#pragma unroll
      for (int mb = 0; mb < 2; ++mb)
#pragma unroll
        for (int nb = 0; nb < 4; ++nb)
          sc[mb][nb] = __builtin_amdgcn_mfma_f32_16x16x32_bf16(qf[mb][kk], kf[kk][nb], sc[mb][nb], 0, 0, 0);

    // P = exp2(s*c - 4); sigma(key = nb*16+l15) = l15*4+nb -> b64 per row
#pragma unroll
    for (int mb = 0; mb < 2; ++mb)
#pragma unroll
      for (int r = 0; r < 4; ++r) {
        float p0 = EXP2F(fmaf(sc[mb][0][r], cexp, -4.0f));
        float p1 = EXP2F(fmaf(sc[mb][1][r], cexp, -4.0f));
        float p2 = EXP2F(fmaf(sc[mb][2][r], cexp, -4.0f));
        float p3 = EXP2F(fmaf(sc[mb][3][r], cexp, -4.0f));
        uint2 u;
        u.x = pk2bf_fast(p0, p1);
        u.y = pk2bf_fast(p2, p3);
        *(uint2*)(SP + (row0 + mb * 16 + lg * 4 + r) * 72 + l15 * 4) = u;
      }

    // prefetch next kt's K fragments (kf dead after QK; sc dead after exp).
    // Covered by the PV phase + barrier + V staging before next use.
    {
      const int ktn = (kt + 1 < 32) ? kt + 1 : 0;  // last prefetch discarded
#pragma unroll
      for (int kk = 0; kk < 2; ++kk)
#pragma unroll
        for (int nb = 0; nb < 4; ++nb)
          kf[kk][nb] = *(const short8*)(kbase + ktn * 4096 + nb * 1024 + kk * 32);
    }

    // ctx += P @ [V | 1]  (same-wave LDS write->read, in-order)
#pragma unroll
    for (int kk = 0; kk < 2; ++kk) {
      short8 pa[2], vb[4];
#pragma unroll
      for (int mb = 0; mb < 2; ++mb)
        pa[mb] = *(const short8*)(SP + (row0 + mb * 16 + l15) * 72 + kk * 32 + lg * 8);
#pragma unroll
      for (int nd = 0; nd < 4; ++nd)
        vb[nd] = *(const short8*)(Vts + (nd * 16 + l15) * 64 + ((((kk * 4 + lg) << 3)) ^ sw));
#pragma unroll
      for (int mb = 0; mb < 2; ++mb) {
#pragma unroll
        for (int nd = 0; nd < 4; ++nd)
          acc[mb][nd] = __builtin_amdgcn_mfma_f32_16x16x32_bf16(pa[mb], vb[nd], acc[mb][nd], 0, 0, 0);
        acc[mb][4] = __builtin_amdgcn_mfma_f32_16x16x32_bf16(pa[mb], ones8, acc[mb][4], 0, 0, 0);
      }
    }
  }

  // epilogue: l = acc[mb][4][r] (replicated across cols); ctx stored
  // chunk-swizzled by s&7 for gemm_out's fragment reads.
#pragma unroll
  for (int mb = 0; mb < 2; ++mb)
#pragma unroll
    for (int r = 0; r < 4; ++r) {
      float inv = 1.0f / acc[mb][4][r];
      int s = qt * 128 + row0 + mb * 16 + lg * 4 + r;
      int s7 = s & 7;
      u16* dst = ctxg + (b * 2048 + s) * 1024 + h * 64;
#pragma unroll
      for (int nd = 0; nd < 4; ++nd) {
        int d = nd * 16 + l15;
        int dcol = (((d >> 3) ^ s7) << 3) | (d & 7);
        dst[dcol] = f2bf(acc[mb][nd][r] * inv);
      }
    }
}

// ------------------------------------------------------------ out projection
// out[m,n] = sum_k ctx[m,k]*Wo[n,k] + bo[n], fp32 out. 64x64 tiles, grid
// (16,64) = 1024 blocks, 32 KB LDS -> 4 blocks/CU (16 waves).
__global__ __launch_bounds__(256) void gemm_out(
    const u16* __restrict__ cb, const u16* __restrict__ wob,
    const float* __restrict__ bo, float* __restrict__ out) {
  __shared__ u16 smem[16384];  // As[2][4096] | Bs[2][4096] = 32 KB
  u16* As = smem;
  u16* Bs = smem + 8192;
  const int tid = threadIdx.x, lane = tid & 63;
  const int wid = tid >> 6;
  const int l15 = lane & 15, lg = lane >> 4;
  const int m0 = blockIdx.y * 64, n0 = blockIdx.x * 64;
  const int sw = ((l15 & 7) << 3);

  f32x4 acc[4] = {};

#pragma unroll
  for (int i = 0; i < 2; ++i) {
    int c = i * 256 + tid;
    gl2lds16(cb  + (m0 + (c >> 3)) * 1024 + (c & 7) * 8, As + c * 8);
    gl2lds16(wob + (n0 + (c >> 3)) * 1024 + (c & 7) * 8, Bs + c * 8);
  }

  for (int k0 = 0; k0 < 1024; k0 += 64) {
    const int p = (k0 >> 6) & 1;
    __syncthreads();
    if (k0 < 960) {
      u16* An = As + (1 - p) * 4096;
      u16* Bn = Bs + (1 - p) * 4096;
#pragma unroll
      for (int i = 0; i < 2; ++i) {
        int c = i * 256 + tid;
        gl2lds16(cb  + (m0 + (c >> 3)) * 1024 + k0 + 64 + (c & 7) * 8, An + c * 8);
        gl2lds16(wob + (n0 + (c >> 3)) * 1024 + k0 + 64 + (c & 7) * 8, Bn + c * 8);
      }
    }
    const u16* Ap = As + p * 4096;
    const u16* Bp = Bs + p * 4096;
#pragma unroll
    for (int kk = 0; kk < 2; ++kk) {
      short8 af, bf[4];
      af = *(const short8*)(Ap + (wid * 16 + l15) * 64 + ((((kk * 4 + lg) << 3)) ^ sw));
#pragma unroll
      for (int nb = 0; nb < 4; ++nb)
        bf[nb] = *(const short8*)(Bp + (nb * 16 + l15) * 64 + ((((kk * 4 + lg) << 3)) ^ sw));
#pragma unroll
      for (int nb = 0; nb < 4; ++nb)
        acc[nb] = __builtin_amdgcn_mfma_f32_16x16x32_bf16(af, bf[nb], acc[nb], 0, 0, 0);
    }
  }

#pragma unroll
  for (int nb = 0; nb < 4; ++nb)
#pragma unroll
    for (int r = 0; r < 4; ++r) {
      int m = m0 + wid * 16 + lg * 4 + r;
      int n = n0 + nb * 16 + l15;
      out[m * 1024 + n] = acc[nb][r] + bo[n];
    }
}

// --------------------------------------------------------------------- launch
extern "C" void kernel_launch(void* const* d_in, const int* in_sizes, int n_in,
                              void* d_out, int out_size, void* d_ws, size_t ws_size,
                              hipStream_t stream) {
  const float* x  = (const float*)d_in[0];
  const float* wq = (const float*)d_in[1];
  const float* bq = (const float*)d_in[2];
  const float* wk = (const float*)d_in[3];
  const float* bk = (const float*)d_in[4];
  const float* wv = (const float*)d_in[5];
  const float* bv = (const float*)d_in[6];
  const float* wo = (const float*)d_in[7];
  const float* bo = (const float*)d_in[8];

  if (ws_size < (size_t)24 * 1024 * 1024 * 2) return;
  u16* xb   = (u16*)d_ws;              // chunk-swizzled
  u16* wqb  = xb  + (4u << 20);        // chunk-swizzled
  u16* wkb  = wqb + (1u << 20);
  u16* wvb  = wkb + (1u << 20);
  u16* wob  = wvb + (1u << 20);
  u16* qb   = wob + (1u << 20);        // plain [B,NH,S,D]
  u16* kb   = qb  + (4u << 20);        // plain [B,NH,S,D]
  u16* vtb  = kb  + (4u << 20);        // V^T [B,NH,D,Sperm], chunk-swizzled
  u16* ctxb = vtb + (4u << 20);        // chunk-swizzled [B,S,H]

  cvt_kernel<<<dim3(512, 8, 1), 256, 0, stream>>>(x, wq, wk, wv, wo, xb, wqb, wkb, wvb, wob);
  gemm_qkv<<<dim3(16, 32, 3), 256, 0, stream>>>(xb, wqb, wkb, wvb, bq, bk, bv, qb, kb, vtb);
  attn_kernel<<<dim3(16, 16, 2), 256, 0, stream>>>(qb, kb, vtb, ctxb);
  gemm_out<<<dim3(16, 64, 1), 256, 0, stream>>>(ctxb, wob, bo, (float*)d_out);
}

// Round 10
// 180.256 us; speedup vs baseline: 1.2018x; 1.1244x over previous
//
#include <hip/hip_runtime.h>
#include <cstdint>

typedef unsigned short u16;
typedef __attribute__((ext_vector_type(8))) short short8;
typedef __attribute__((ext_vector_type(4))) float f32x4;

#if __has_builtin(__builtin_amdgcn_exp2f)
#define EXP2F(x) __builtin_amdgcn_exp2f(x)
#else
#define EXP2F(x) exp2f(x)
#endif

// fp32 -> bf16 bits, round-to-nearest-even
__device__ inline u16 f2bf(float f) {
  union { float f; unsigned u; } v; v.f = f;
  unsigned u = v.u;
  return (u16)((u + 0x7fffu + ((u >> 16) & 1u)) >> 16);
}

// pack two fp32 -> bf16x2 (a -> low); round-half-up (P>0 only, 1ulp vs RNE)
__device__ inline unsigned pk2bf_fast(float a, float b) {
  union { float f; unsigned u; } ua, ub; ua.f = a; ub.f = b;
  return __builtin_amdgcn_perm(ub.u + 0x8000u, ua.u + 0x8000u, 0x07060302u);
}

// async global -> LDS, 16B per lane (contiguous landing order only)
__device__ inline void gl2lds16(const void* g, void* l) {
  __builtin_amdgcn_global_load_lds(
      (const __attribute__((address_space(1))) unsigned int*)(unsigned long long)(uintptr_t)g,
      (__attribute__((address_space(3))) unsigned int*)(unsigned int)(uintptr_t)l,
      16, 0, 0);
}

// XOR chunk swizzle: within each 64-elem K-slice of a row, 16B chunk c of row
// r is stored at position c ^ (r & 7). gl2lds staging copies slices verbatim;
// fragment reads at chunk' = (kk*4+lg) ^ (l15&7) are phase-conflict-free.

// ---------------------------------------------------------------- cvt kernel
__global__ __launch_bounds__(256) void cvt_kernel(
    const float* __restrict__ x,
    const float* __restrict__ wq, const float* __restrict__ wk,
    const float* __restrict__ wv, const float* __restrict__ wo,
    u16* __restrict__ xb, u16* __restrict__ wqb, u16* __restrict__ wkb,
    u16* __restrict__ wvb, u16* __restrict__ wob) {
  const int y = blockIdx.y;
  const int Q = 1 << 20;
  const float* src;
  u16* dst;
  if (y < 4)       { src = x + y * Q; dst = xb + y * Q; }
  else if (y == 4) { src = wq; dst = wqb; }
  else if (y == 5) { src = wk; dst = wkb; }
  else if (y == 6) { src = wv; dst = wvb; }
  else             { src = wo; dst = wob; }
  const int i = (blockIdx.x * 256 + threadIdx.x) * 8;
  float4 a = *(const float4*)(src + i);
  float4 b = *(const float4*)(src + i + 4);
  short8 o;
  o[0] = (short)f2bf(a.x); o[1] = (short)f2bf(a.y);
  o[2] = (short)f2bf(a.z); o[3] = (short)f2bf(a.w);
  o[4] = (short)f2bf(b.x); o[5] = (short)f2bf(b.y);
  o[6] = (short)f2bf(b.z); o[7] = (short)f2bf(b.w);
  const int j = (i & ~63) | (((((i >> 3) & 7) ^ ((i >> 10) & 7))) << 3);
  *(short8*)(dst + j) = o;
}

// ------------------------------------------------------------ QKV projection
// Z-FUSED NT GEMM: one block computes the Q, K and V 128m x 64n tiles for its
// (m0,n0) -> x staged ONCE feeds 3 B-panels, 48 MFMA/wave per k-iter against
// one barrier. grid (16, 32) = 512 blocks, 80 KB LDS -> 2 blocks/CU.
// Double-buffered gl2lds, one barrier per K-iter.
// Q out: plain [B,NH,S,D], PRE-SCALED by log2(e)/8 (softmax fold).
// K out: [B,NH,S,D] chunk-swizzled by s&7 (attn LDS frag reads).
// V out: V^T [B,NH,D,Sperm] (sigma(s)=(s&15)*4+(s>>4)&3), swizzled by d&7.
__global__ __launch_bounds__(256, 2) void gemm_qkv(
    const u16* __restrict__ xb,
    const u16* __restrict__ wqb, const u16* __restrict__ wkb, const u16* __restrict__ wvb,
    const float* __restrict__ bq, const float* __restrict__ bk, const float* __restrict__ bv,
    u16* __restrict__ qo, u16* __restrict__ ko, u16* __restrict__ vto) {
  __shared__ u16 smem[40960];        // As[2][8192] | Bs[2][3][4096] = 80 KB
  u16* As = smem;                    // + p*8192
  u16* Bs = smem + 16384;            // + p*12288 + z*4096
  const int tid = threadIdx.x, lane = tid & 63;
  const int wid = tid >> 6;
  const int l15 = lane & 15, lg = lane >> 4;
  const int m0 = blockIdx.y * 128, n0 = blockIdx.x * 64;
  const int sw = ((l15 & 7) << 3);
  const u16* Wz[3] = {wqb, wkb, wvb};

  f32x4 acc[3][2][4] = {};

  // prologue: stage k0=0 into buffer 0
#pragma unroll
  for (int i = 0; i < 4; ++i) {
    int c = i * 256 + tid;
    gl2lds16(xb + (m0 + (c >> 3)) * 1024 + (c & 7) * 8, As + c * 8);
  }
#pragma unroll
  for (int z = 0; z < 3; ++z)
#pragma unroll
    for (int i = 0; i < 2; ++i) {
      int c = i * 256 + tid;
      gl2lds16(Wz[z] + (n0 + (c >> 3)) * 1024 + (c & 7) * 8, Bs + z * 4096 + c * 8);
    }

  for (int k0 = 0; k0 < 1024; k0 += 64) {
    const int p = (k0 >> 6) & 1;
    __syncthreads();  // drains vmcnt -> buf p ready
    if (k0 < 960) {
      u16* An = As + (1 - p) * 8192;
      u16* Bn = Bs + (1 - p) * 12288;
#pragma unroll
      for (int i = 0; i < 4; ++i) {
        int c = i * 256 + tid;
        gl2lds16(xb + (m0 + (c >> 3)) * 1024 + k0 + 64 + (c & 7) * 8, An + c * 8);
      }
#pragma unroll
      for (int z = 0; z < 3; ++z)
#pragma unroll
        for (int i = 0; i < 2; ++i) {
          int c = i * 256 + tid;
          gl2lds16(Wz[z] + (n0 + (c >> 3)) * 1024 + k0 + 64 + (c & 7) * 8, Bn + z * 4096 + c * 8);
        }
    }
    const u16* Ap = As + p * 8192;
    const u16* Bp = Bs + p * 12288;
#pragma unroll
    for (int kk = 0; kk < 2; ++kk) {
      short8 af[2], bf[3][4];
#pragma unroll
      for (int mb = 0; mb < 2; ++mb)
        af[mb] = *(const short8*)(Ap + (wid * 32 + mb * 16 + l15) * 64 + ((((kk * 4 + lg) << 3)) ^ sw));
#pragma unroll
      for (int z = 0; z < 3; ++z)
#pragma unroll
        for (int nb = 0; nb < 4; ++nb)
          bf[z][nb] = *(const short8*)(Bp + z * 4096 + (nb * 16 + l15) * 64 + ((((kk * 4 + lg) << 3)) ^ sw));
#pragma unroll
      for (int z = 0; z < 3; ++z)
#pragma unroll
        for (int mb = 0; mb < 2; ++mb)
#pragma unroll
          for (int nb = 0; nb < 4; ++nb)
            acc[z][mb][nb] = __builtin_amdgcn_mfma_f32_16x16x32_bf16(af[mb], bf[z][nb], acc[z][mb][nb], 0, 0, 0);
    }
  }

  const float cexp = 0.18033688011112042f;  // log2(e)/8 folded into Q

  // Q epilogue (plain layout, pre-scaled)
#pragma unroll
  for (int mb = 0; mb < 2; ++mb)
#pragma unroll
    for (int nb = 0; nb < 4; ++nb)
#pragma unroll
      for (int r = 0; r < 4; ++r) {
        int m = m0 + wid * 32 + mb * 16 + lg * 4 + r;  // b*2048 + s
        int n = n0 + nb * 16 + l15;                    // h*64 + d
        float v = (acc[0][mb][nb][r] + bq[n]) * cexp;
        int b = m >> 11, s = m & 2047, hh = n >> 6, d = n & 63;
        qo[((b * 16 + hh) * 2048 + s) * 64 + d] = f2bf(v);
      }

  // K epilogue (chunk-swizzled by s&7)
#pragma unroll
  for (int mb = 0; mb < 2; ++mb)
#pragma unroll
    for (int nb = 0; nb < 4; ++nb)
#pragma unroll
      for (int r = 0; r < 4; ++r) {
        int m = m0 + wid * 32 + mb * 16 + lg * 4 + r;
        int n = n0 + nb * 16 + l15;
        float v = acc[1][mb][nb][r] + bk[n];
        int b = m >> 11, s = m & 2047, hh = n >> 6, d = n & 63;
        int dcol = (((d >> 3) ^ (s & 7)) << 3) | (d & 7);
        ko[((b * 16 + hh) * 2048 + s) * 64 + dcol] = f2bf(v);
      }

  // V epilogue: wave-pair shared 64(d) x 72 transpose buffers, then coalesced
  // 16B global stores in sigma layout, chunk-swizzled by d&7.
  __syncthreads();  // all waves done with As/Bs
  {
    u16* wbuf = smem + (wid >> 1) * 4608;
    const int so = (wid & 1) * 2;
#pragma unroll
    for (int mb = 0; mb < 2; ++mb)
#pragma unroll
      for (int nb = 0; nb < 4; ++nb) {
        int n = n0 + nb * 16 + l15;
        float bn = bv[n];
        int dl = nb * 16 + l15;
#pragma unroll
        for (int r = 0; r < 4; ++r) {
          int sig = (lg * 4 + r) * 4 + so + mb;  // sigma of s within 64-block
          wbuf[dl * 72 + sig] = f2bf(acc[2][mb][nb][r] + bn);
        }
      }
    __syncthreads();  // cross-wave transpose complete
    int hh = n0 >> 6;
    int bb = m0 >> 11;
    int sbase = m0 & 2047;
#pragma unroll
    for (int i = 0; i < 4; ++i) {
      int idx = i * 256 + tid;           // 1024 chunks = 2 bufs x 64 x 8
      int p2 = idx >> 9, rem = idx & 511;
      int dl = rem >> 3, c = rem & 7;
      short8 vv = *(const short8*)(smem + p2 * 4608 + dl * 72 + c * 8);
      int cs = c ^ (dl & 7);             // chunk swizzle by d&7
      *(short8*)(vto + ((bb * 16 + hh) * 64 + dl) * 2048 + sbase + p2 * 64 + cs * 8) = vv;
    }
  }
}

// ---------------------------------------------------------------- attention
// r7 structure: flash-style, Q-tile 128 x K-tile 64, grid (16,16,2), 256 thr
// (4 waves x 32 q-rows). K+V^T staged via gl2lds into double-buffered LDS,
// ONE barrier per kt. Fragment reads conflict-free via baked chunk swizzle.
// Q fragments direct from global (pre-scaled by log2(e)/8 in gemm_qkv) ->
// softmax is a bare exp2 (fixed-max offset cancels in ctx/l). Row-sum via
// ones-register B operand.
__global__ __launch_bounds__(256, 2) void attn_kernel(
    const u16* __restrict__ qg, const u16* __restrict__ kg,
    const u16* __restrict__ vtg, u16* __restrict__ ctxg) {
  const int h = blockIdx.x, qt = blockIdx.y, b = blockIdx.z;
  const int bh = b * 16 + h;
  const u16* Qg = qg + (bh * 2048 + qt * 128) * 64;
  const u16* Kg = kg + bh * 2048 * 64;
  const u16* Vg = vtg + bh * 64 * 2048;

  __shared__ u16 SP[128 * 72];   // P round-trip; wave-private 32-row strips
  __shared__ u16 KV[2][8192];    // [p][0:4096)=K tile, [p][4096:8192)=V^T

  const int tid = threadIdx.x, lane = tid & 63, wid = tid >> 6;
  const int l15 = lane & 15, lg = lane >> 4;
  const int row0 = wid * 32;
  const int sw = ((l15 & 7) << 3);

  // Q fragments direct from global (plain layout, reused all 32 kt)
  short8 qf[2][2];
#pragma unroll
  for (int mb = 0; mb < 2; ++mb)
#pragma unroll
    for (int kk = 0; kk < 2; ++kk)
      qf[mb][kk] = *(const short8*)(Qg + (row0 + mb * 16 + l15) * 64 + kk * 32 + lg * 8);

  short8 ones8;
#pragma unroll
  for (int j = 0; j < 8; ++j) ones8[j] = (short)0x3F80;  // bf16 1.0

  // prologue: stage kt=0 into buffer 0
#pragma unroll
  for (int i = 0; i < 2; ++i) {
    int c = i * 256 + tid;
    gl2lds16(Kg + c * 8, &KV[0][c * 8]);
    gl2lds16(Vg + (c >> 3) * 2048 + (c & 7) * 8, &KV[0][4096 + c * 8]);
  }

  f32x4 acc[2][5] = {};  // nd 0..3 = ctx, nd 4 = row-sum

  for (int kt = 0; kt < 32; ++kt) {
    const int p = kt & 1;
    __syncthreads();  // drains vmcnt -> buf p ready
    if (kt < 31) {
#pragma unroll
      for (int i = 0; i < 2; ++i) {
        int c = i * 256 + tid;
        gl2lds16(Kg + (kt + 1) * 4096 + c * 8, &KV[1 - p][c * 8]);
        gl2lds16(Vg + (c >> 3) * 2048 + (kt + 1) * 64 + (c & 7) * 8, &KV[1 - p][4096 + c * 8]);
      }
    }
    const u16* Ks = &KV[p][0];
    const u16* Vts = &KV[p][4096];

    // S = Q K^T (Q pre-scaled)
    f32x4 sc[2][4] = {};
#pragma unroll
    for (int kk = 0; kk < 2; ++kk) {
      short8 bfr[4];
#pragma unroll
      for (int nb = 0; nb < 4; ++nb)
        bfr[nb] = *(const short8*)(Ks + (nb * 16 + l15) * 64 + ((((kk * 4 + lg) << 3)) ^ sw));
#pragma unroll
      for (int mb = 0; mb < 2; ++mb)
#pragma unroll
        for (int nb = 0; nb < 4; ++nb)
          sc[mb][nb] = __builtin_amdgcn_mfma_f32_16x16x32_bf16(qf[mb][kk], bfr[nb], sc[mb][nb], 0, 0, 0);
    }

    // P = exp2(s)  (offset-free; constant cancels in ctx/l)
    // sigma(key = nb*16+l15) = l15*4+nb -> one b64 write per row
#pragma unroll
    for (int mb = 0; mb < 2; ++mb)
#pragma unroll
      for (int r = 0; r < 4; ++r) {
        float p0 = EXP2F(sc[mb][0][r]);
        float p1 = EXP2F(sc[mb][1][r]);
        float p2 = EXP2F(sc[mb][2][r]);
        float p3 = EXP2F(sc[mb][3][r]);
        uint2 u;
        u.x = pk2bf_fast(p0, p1);
        u.y = pk2bf_fast(p2, p3);
        *(uint2*)(SP + (row0 + mb * 16 + lg * 4 + r) * 72 + l15 * 4) = u;
      }

    // ctx += P @ [V | 1]  (same-wave LDS write->read, in-order)
#pragma unroll
    for (int kk = 0; kk < 2; ++kk) {
      short8 pa[2], vb[4];
#pragma unroll
      for (int mb = 0; mb < 2; ++mb)
        pa[mb] = *(const short8*)(SP + (row0 + mb * 16 + l15) * 72 + kk * 32 + lg * 8);
#pragma unroll
      for (int nd = 0; nd < 4; ++nd)
        vb[nd] = *(const short8*)(Vts + (nd * 16 + l15) * 64 + ((((kk * 4 + lg) << 3)) ^ sw));
#pragma unroll
      for (int mb = 0; mb < 2; ++mb) {
#pragma unroll
        for (int nd = 0; nd < 4; ++nd)
          acc[mb][nd] = __builtin_amdgcn_mfma_f32_16x16x32_bf16(pa[mb], vb[nd], acc[mb][nd], 0, 0, 0);
        acc[mb][4] = __builtin_amdgcn_mfma_f32_16x16x32_bf16(pa[mb], ones8, acc[mb][4], 0, 0, 0);
      }
    }
  }

  // epilogue: l = acc[mb][4][r] (replicated across cols); ctx stored
  // chunk-swizzled by s&7 for gemm_out's fragment reads.
#pragma unroll
  for (int mb = 0; mb < 2; ++mb)
#pragma unroll
    for (int r = 0; r < 4; ++r) {
      float inv = 1.0f / acc[mb][4][r];
      int s = qt * 128 + row0 + mb * 16 + lg * 4 + r;
      int s7 = s & 7;
      u16* dst = ctxg + (b * 2048 + s) * 1024 + h * 64;
#pragma unroll
      for (int nd = 0; nd < 4; ++nd) {
        int d = nd * 16 + l15;
        int dcol = (((d >> 3) ^ s7) << 3) | (d & 7);
        dst[dcol] = f2bf(acc[mb][nd][r] * inv);
      }
    }
}

// ------------------------------------------------------------ out projection
// out[m,n] = sum_k ctx[m,k]*Wo[n,k] + bo[n], fp32 out. 64x64 tiles, grid
// (16,64) = 1024 blocks, 32 KB LDS -> 4 blocks/CU (16 waves).
__global__ __launch_bounds__(256) void gemm_out(
    const u16* __restrict__ cb, const u16* __restrict__ wob,
    const float* __restrict__ bo, float* __restrict__ out) {
  __shared__ u16 smem[16384];  // As[2][4096] | Bs[2][4096] = 32 KB
  u16* As = smem;
  u16* Bs = smem + 8192;
  const int tid = threadIdx.x, lane = tid & 63;
  const int wid = tid >> 6;
  const int l15 = lane & 15, lg = lane >> 4;
  const int m0 = blockIdx.y * 64, n0 = blockIdx.x * 64;
  const int sw = ((l15 & 7) << 3);

  f32x4 acc[4] = {};

#pragma unroll
  for (int i = 0; i < 2; ++i) {
    int c = i * 256 + tid;
    gl2lds16(cb  + (m0 + (c >> 3)) * 1024 + (c & 7) * 8, As + c * 8);
    gl2lds16(wob + (n0 + (c >> 3)) * 1024 + (c & 7) * 8, Bs + c * 8);
  }

  for (int k0 = 0; k0 < 1024; k0 += 64) {
    const int p = (k0 >> 6) & 1;
    __syncthreads();
    if (k0 < 960) {
      u16* An = As + (1 - p) * 4096;
      u16* Bn = Bs + (1 - p) * 4096;
#pragma unroll
      for (int i = 0; i < 2; ++i) {
        int c = i * 256 + tid;
        gl2lds16(cb  + (m0 + (c >> 3)) * 1024 + k0 + 64 + (c & 7) * 8, An + c * 8);
        gl2lds16(wob + (n0 + (c >> 3)) * 1024 + k0 + 64 + (c & 7) * 8, Bn + c * 8);
      }
    }
    const u16* Ap = As + p * 4096;
    const u16* Bp = Bs + p * 4096;
#pragma unroll
    for (int kk = 0; kk < 2; ++kk) {
      short8 af, bf[4];
      af = *(const short8*)(Ap + (wid * 16 + l15) * 64 + ((((kk * 4 + lg) << 3)) ^ sw));
#pragma unroll
      for (int nb = 0; nb < 4; ++nb)
        bf[nb] = *(const short8*)(Bp + (nb * 16 + l15) * 64 + ((((kk * 4 + lg) << 3)) ^ sw));
#pragma unroll
      for (int nb = 0; nb < 4; ++nb)
        acc[nb] = __builtin_amdgcn_mfma_f32_16x16x32_bf16(af, bf[nb], acc[nb], 0, 0, 0);
    }
  }

#pragma unroll
  for (int nb = 0; nb < 4; ++nb)
#pragma unroll
    for (int r = 0; r < 4; ++r) {
      int m = m0 + wid * 16 + lg * 4 + r;
      int n = n0 + nb * 16 + l15;
      out[m * 1024 + n] = acc[nb][r] + bo[n];
    }
}

// --------------------------------------------------------------------- launch
extern "C" void kernel_launch(void* const* d_in, const int* in_sizes, int n_in,
                              void* d_out, int out_size, void* d_ws, size_t ws_size,
                              hipStream_t stream) {
  const float* x  = (const float*)d_in[0];
  const float* wq = (const float*)d_in[1];
  const float* bq = (const float*)d_in[2];
  const float* wk = (const float*)d_in[3];
  const float* bk = (const float*)d_in[4];
  const float* wv = (const float*)d_in[5];
  const float* bv = (const float*)d_in[6];
  const float* wo = (const float*)d_in[7];
  const float* bo = (const float*)d_in[8];

  if (ws_size < (size_t)24 * 1024 * 1024 * 2) return;
  u16* xb   = (u16*)d_ws;              // chunk-swizzled
  u16* wqb  = xb  + (4u << 20);        // chunk-swizzled
  u16* wkb  = wqb + (1u << 20);
  u16* wvb  = wkb + (1u << 20);
  u16* wob  = wvb + (1u << 20);
  u16* qb   = wob + (1u << 20);        // plain [B,NH,S,D], pre-scaled
  u16* kb   = qb  + (4u << 20);        // chunk-swizzled [B,NH,S,D]
  u16* vtb  = kb  + (4u << 20);        // V^T [B,NH,D,Sperm], chunk-swizzled
  u16* ctxb = vtb + (4u << 20);        // chunk-swizzled [B,S,H]

  cvt_kernel<<<dim3(512, 8, 1), 256, 0, stream>>>(x, wq, wk, wv, wo, xb, wqb, wkb, wvb, wob);
  gemm_qkv<<<dim3(16, 32, 1), 256, 0, stream>>>(xb, wqb, wkb, wvb, bq, bk, bv, qb, kb, vtb);
  attn_kernel<<<dim3(16, 16, 2), 256, 0, stream>>>(qb, kb, vtb, ctxb);
  gemm_out<<<dim3(16, 64, 1), 256, 0, stream>>>(ctxb, wob, bo, (float*)d_out);
}

// Round 11
// 169.886 us; speedup vs baseline: 1.2752x; 1.0610x over previous
//
#include <hip/hip_runtime.h>
#include <cstdint>

typedef unsigned short u16;
typedef __attribute__((ext_vector_type(8))) short short8;
typedef __attribute__((ext_vector_type(4))) float f32x4;
typedef __attribute__((ext_vector_type(4))) unsigned short ushort4v;

#if __has_builtin(__builtin_amdgcn_exp2f)
#define EXP2F(x) __builtin_amdgcn_exp2f(x)
#else
#define EXP2F(x) exp2f(x)
#endif

// fp32 -> bf16 bits, round-to-nearest-even
__device__ inline u16 f2bf(float f) {
  union { float f; unsigned u; } v; v.f = f;
  unsigned u = v.u;
  return (u16)((u + 0x7fffu + ((u >> 16) & 1u)) >> 16);
}

// pack two fp32 -> bf16x2 (a -> low); round-half-up (P>0 only, 1ulp vs RNE)
__device__ inline unsigned pk2bf_fast(float a, float b) {
  union { float f; unsigned u; } ua, ub; ua.f = a; ub.f = b;
  return __builtin_amdgcn_perm(ub.u + 0x8000u, ua.u + 0x8000u, 0x07060302u);
}

// async global -> LDS, 16B per lane (contiguous landing order only)
__device__ inline void gl2lds16(const void* g, void* l) {
  __builtin_amdgcn_global_load_lds(
      (const __attribute__((address_space(1))) unsigned int*)(unsigned long long)(uintptr_t)g,
      (__attribute__((address_space(3))) unsigned int*)(unsigned int)(uintptr_t)l,
      16, 0, 0);
}

// XOR chunk swizzle: within each 64-elem K-slice of a row, 16B chunk c of row
// r is stored at position c ^ (r & 7). gl2lds staging copies slices verbatim;
// fragment reads at chunk' = (kk*4+lg) ^ (l15&7) are phase-conflict-free.

// ---------------------------------------------------------------- cvt kernel
__global__ __launch_bounds__(256) void cvt_kernel(
    const float* __restrict__ x,
    const float* __restrict__ wq, const float* __restrict__ wk,
    const float* __restrict__ wv, const float* __restrict__ wo,
    u16* __restrict__ xb, u16* __restrict__ wqb, u16* __restrict__ wkb,
    u16* __restrict__ wvb, u16* __restrict__ wob) {
  const int y = blockIdx.y;
  const int Q = 1 << 20;
  const float* src;
  u16* dst;
  if (y < 4)       { src = x + y * Q; dst = xb + y * Q; }
  else if (y == 4) { src = wq; dst = wqb; }
  else if (y == 5) { src = wk; dst = wkb; }
  else if (y == 6) { src = wv; dst = wvb; }
  else             { src = wo; dst = wob; }
  const int i = (blockIdx.x * 256 + threadIdx.x) * 8;
  float4 a = *(const float4*)(src + i);
  float4 b = *(const float4*)(src + i + 4);
  short8 o;
  o[0] = (short)f2bf(a.x); o[1] = (short)f2bf(a.y);
  o[2] = (short)f2bf(a.z); o[3] = (short)f2bf(a.w);
  o[4] = (short)f2bf(b.x); o[5] = (short)f2bf(b.y);
  o[6] = (short)f2bf(b.z); o[7] = (short)f2bf(b.w);
  const int j = (i & ~63) | (((((i >> 3) & 7) ^ ((i >> 10) & 7))) << 3);
  *(short8*)(dst + j) = o;
}

// ------------------------------------------------------------ QKV projection
// Z-FUSED NT GEMM: x staged once feeds 3 B-panels, 48 MFMA/wave per k-iter.
// grid (16, 32) = 512 blocks, 80 KB LDS -> 2 blocks/CU. Double-buffered
// gl2lds, one barrier per K-iter.
// Q out: plain [B,NH,S,D], PRE-SCALED by log2(e)/8 (softmax fold).
// K out: [B,NH,S,D] chunk-swizzled by s&7.
// V out: V^T [B,NH,D,Sperm]; key slot within each 64-key block:
//   key = slice*32 + t*16 + quad*4 + r  ->  slot = slice*32 + quad*8 + t*4 + r
// (matches attn's P B-operand key order); chunk-swizzled by d&7.
__global__ __launch_bounds__(256, 2) void gemm_qkv(
    const u16* __restrict__ xb,
    const u16* __restrict__ wqb, const u16* __restrict__ wkb, const u16* __restrict__ wvb,
    const float* __restrict__ bq, const float* __restrict__ bk, const float* __restrict__ bv,
    u16* __restrict__ qo, u16* __restrict__ ko, u16* __restrict__ vto) {
  __shared__ u16 smem[40960];        // As[2][8192] | Bs[2][3][4096] = 80 KB
  u16* As = smem;                    // + p*8192
  u16* Bs = smem + 16384;            // + p*12288 + z*4096
  const int tid = threadIdx.x, lane = tid & 63;
  const int wid = tid >> 6;
  const int l15 = lane & 15, lg = lane >> 4;
  const int m0 = blockIdx.y * 128, n0 = blockIdx.x * 64;
  const int sw = ((l15 & 7) << 3);
  const u16* Wz[3] = {wqb, wkb, wvb};

  f32x4 acc[3][2][4] = {};

  // prologue: stage k0=0 into buffer 0
#pragma unroll
  for (int i = 0; i < 4; ++i) {
    int c = i * 256 + tid;
    gl2lds16(xb + (m0 + (c >> 3)) * 1024 + (c & 7) * 8, As + c * 8);
  }
#pragma unroll
  for (int z = 0; z < 3; ++z)
#pragma unroll
    for (int i = 0; i < 2; ++i) {
      int c = i * 256 + tid;
      gl2lds16(Wz[z] + (n0 + (c >> 3)) * 1024 + (c & 7) * 8, Bs + z * 4096 + c * 8);
    }

  for (int k0 = 0; k0 < 1024; k0 += 64) {
    const int p = (k0 >> 6) & 1;
    __syncthreads();  // drains vmcnt -> buf p ready
    if (k0 < 960) {
      u16* An = As + (1 - p) * 8192;
      u16* Bn = Bs + (1 - p) * 12288;
#pragma unroll
      for (int i = 0; i < 4; ++i) {
        int c = i * 256 + tid;
        gl2lds16(xb + (m0 + (c >> 3)) * 1024 + k0 + 64 + (c & 7) * 8, An + c * 8);
      }
#pragma unroll
      for (int z = 0; z < 3; ++z)
#pragma unroll
        for (int i = 0; i < 2; ++i) {
          int c = i * 256 + tid;
          gl2lds16(Wz[z] + (n0 + (c >> 3)) * 1024 + k0 + 64 + (c & 7) * 8, Bn + z * 4096 + c * 8);
        }
    }
    const u16* Ap = As + p * 8192;
    const u16* Bp = Bs + p * 12288;
#pragma unroll
    for (int kk = 0; kk < 2; ++kk) {
      short8 af[2], bf[3][4];
#pragma unroll
      for (int mb = 0; mb < 2; ++mb)
        af[mb] = *(const short8*)(Ap + (wid * 32 + mb * 16 + l15) * 64 + ((((kk * 4 + lg) << 3)) ^ sw));
#pragma unroll
      for (int z = 0; z < 3; ++z)
#pragma unroll
        for (int nb = 0; nb < 4; ++nb)
          bf[z][nb] = *(const short8*)(Bp + z * 4096 + (nb * 16 + l15) * 64 + ((((kk * 4 + lg) << 3)) ^ sw));
#pragma unroll
      for (int z = 0; z < 3; ++z)
#pragma unroll
        for (int mb = 0; mb < 2; ++mb)
#pragma unroll
          for (int nb = 0; nb < 4; ++nb)
            acc[z][mb][nb] = __builtin_amdgcn_mfma_f32_16x16x32_bf16(af[mb], bf[z][nb], acc[z][mb][nb], 0, 0, 0);
    }
  }

  const float cexp = 0.18033688011112042f;  // log2(e)/8 folded into Q

  // Q epilogue (plain layout, pre-scaled)
#pragma unroll
  for (int mb = 0; mb < 2; ++mb)
#pragma unroll
    for (int nb = 0; nb < 4; ++nb)
#pragma unroll
      for (int r = 0; r < 4; ++r) {
        int m = m0 + wid * 32 + mb * 16 + lg * 4 + r;  // b*2048 + s
        int n = n0 + nb * 16 + l15;                    // h*64 + d
        float v = (acc[0][mb][nb][r] + bq[n]) * cexp;
        int b = m >> 11, s = m & 2047, hh = n >> 6, d = n & 63;
        qo[((b * 16 + hh) * 2048 + s) * 64 + d] = f2bf(v);
      }

  // K epilogue (chunk-swizzled by s&7)
#pragma unroll
  for (int mb = 0; mb < 2; ++mb)
#pragma unroll
    for (int nb = 0; nb < 4; ++nb)
#pragma unroll
      for (int r = 0; r < 4; ++r) {
        int m = m0 + wid * 32 + mb * 16 + lg * 4 + r;
        int n = n0 + nb * 16 + l15;
        float v = acc[1][mb][nb][r] + bk[n];
        int b = m >> 11, s = m & 2047, hh = n >> 6, d = n & 63;
        int dcol = (((d >> 3) ^ (s & 7)) << 3) | (d & 7);
        ko[((b * 16 + hh) * 2048 + s) * 64 + dcol] = f2bf(v);
      }

  // V epilogue: wave-pair shared 64(d) x 72 transpose buffers, slot order per
  // the attn B-operand key permutation, then coalesced 16B global stores.
  __syncthreads();  // all waves done with As/Bs
  {
    u16* wbuf = smem + (wid >> 1) * 4608;
#pragma unroll
    for (int mb = 0; mb < 2; ++mb)
#pragma unroll
      for (int nb = 0; nb < 4; ++nb) {
        int n = n0 + nb * 16 + l15;
        float bn = bv[n];
        int dl = nb * 16 + l15;
#pragma unroll
        for (int r = 0; r < 4; ++r) {
          // key s64 = (wid&1)*32 + mb*16 + lg*4 + r  (slice=wid&1, t=mb, quad=lg)
          int sig = (wid & 1) * 32 + lg * 8 + mb * 4 + r;
          wbuf[dl * 72 + sig] = f2bf(acc[2][mb][nb][r] + bn);
        }
      }
    __syncthreads();  // cross-wave transpose complete
    int hh = n0 >> 6;
    int bb = m0 >> 11;
    int sbase = m0 & 2047;
#pragma unroll
    for (int i = 0; i < 4; ++i) {
      int idx = i * 256 + tid;           // 1024 chunks = 2 bufs x 64 x 8
      int p2 = idx >> 9, rem = idx & 511;
      int dl = rem >> 3, c = rem & 7;
      short8 vv = *(const short8*)(smem + p2 * 4608 + dl * 72 + c * 8);
      int cs = c ^ (dl & 7);             // chunk swizzle by d&7
      *(short8*)(vto + ((bb * 16 + hh) * 64 + dl) * 2048 + sbase + p2 * 64 + cs * 8) = vv;
    }
  }
}

// ---------------------------------------------------------------- attention
// TRANSPOSED dataflow: S^T = K·Q^T (A = K frag from LDS, B = Q regs; C col =
// q = l15, wave-private), P = exp2(S^T) stays in registers and is ALREADY the
// B-operand for O^T = V^T·P (A = V^T frag from LDS; key slots permuted to
// match C-layout key order). l via ones as A operand. P never touches LDS ->
// 16 b128 LDS reads/wave/kt (was 20 b128 + 8 b64) and no LDS round-trip on
// the serial chain. Q pre-scaled by log2(e)/8; offset-free exp2. Epilogue
// transposes O^T through SP (wave-private) for coalesced swizzled ctx stores.
__global__ __launch_bounds__(256, 2) void attn_kernel(
    const u16* __restrict__ qg, const u16* __restrict__ kg,
    const u16* __restrict__ vtg, u16* __restrict__ ctxg) {
  const int h = blockIdx.x, qt = blockIdx.y, b = blockIdx.z;
  const int bh = b * 16 + h;
  const u16* Qg = qg + (bh * 2048 + qt * 128) * 64;
  const u16* Kg = kg + bh * 2048 * 64;
  const u16* Vg = vtg + bh * 64 * 2048;

  __shared__ u16 SP[128 * 72];   // epilogue O-transpose only (wave-private)
  __shared__ u16 KV[2][8192];    // [p][0:4096)=K tile, [p][4096:8192)=V^T

  const int tid = threadIdx.x, lane = tid & 63, wid = tid >> 6;
  const int l15 = lane & 15, lg = lane >> 4;
  const int row0 = wid * 32;     // this wave's 32 query rows
  const int sw = ((l15 & 7) << 3);

  // Q fragments direct from global (pre-scaled; reused all 32 kt).
  // Used as B operand: (n = q = l15, k = d = lg*8.. + kk*32) — same layout.
  short8 qf[2][2];
#pragma unroll
  for (int qtile = 0; qtile < 2; ++qtile)
#pragma unroll
    for (int kk = 0; kk < 2; ++kk)
      qf[qtile][kk] = *(const short8*)(Qg + (row0 + qtile * 16 + l15) * 64 + kk * 32 + lg * 8);

  short8 ones8;
#pragma unroll
  for (int j = 0; j < 8; ++j) ones8[j] = (short)0x3F80;  // bf16 1.0

  // prologue: stage kt=0 into buffer 0
#pragma unroll
  for (int i = 0; i < 2; ++i) {
    int c = i * 256 + tid;
    gl2lds16(Kg + c * 8, &KV[0][c * 8]);
    gl2lds16(Vg + (c >> 3) * 2048 + (c & 7) * 8, &KV[0][4096 + c * 8]);
  }

  f32x4 acc[4][2] = {};   // O^T: [dtile][qtile], C col = q = l15, row = d
  f32x4 accl[2] = {};     // l:  [qtile], all rows identical = l[q=l15]

  for (int kt = 0; kt < 32; ++kt) {
    const int p = kt & 1;
    __syncthreads();  // drains vmcnt -> buf p ready
    if (kt < 31) {
#pragma unroll
      for (int i = 0; i < 2; ++i) {
        int c = i * 256 + tid;
        gl2lds16(Kg + (kt + 1) * 4096 + c * 8, &KV[1 - p][c * 8]);
        gl2lds16(Vg + (c >> 3) * 2048 + (kt + 1) * 64 + (c & 7) * 8, &KV[1 - p][4096 + c * 8]);
      }
    }
    const u16* Ks = &KV[p][0];
    const u16* Vts = &KV[p][4096];

    // S^T = K · Q^T : sc[ktile][qtile], C row = key = lg*4+r, col = q = l15
    f32x4 sc[4][2] = {};
#pragma unroll
    for (int kk = 0; kk < 2; ++kk) {
      short8 kf[4];
#pragma unroll
      for (int ktile = 0; ktile < 4; ++ktile)
        kf[ktile] = *(const short8*)(Ks + (ktile * 16 + l15) * 64 + ((((kk * 4 + lg) << 3)) ^ sw));
#pragma unroll
      for (int ktile = 0; ktile < 4; ++ktile)
#pragma unroll
        for (int qtile = 0; qtile < 2; ++qtile)
          sc[ktile][qtile] = __builtin_amdgcn_mfma_f32_16x16x32_bf16(kf[ktile], qf[qtile][kk], sc[ktile][qtile], 0, 0, 0);
    }

    // P = exp2(S^T) packed in-register into B-operand fragments.
    // B element j of slice: key = slice*32 + (j>=4)*16 + quad*4 + (j&3);
    // V^T slots stored in exactly this order.
    short8 pf[2][2];  // [slice][qtile]
#pragma unroll
    for (int sl = 0; sl < 2; ++sl)
#pragma unroll
      for (int qtile = 0; qtile < 2; ++qtile) {
        union { short8 s; unsigned u[4]; } pu;
        float a0 = EXP2F(sc[sl * 2][qtile][0]),     a1 = EXP2F(sc[sl * 2][qtile][1]);
        float a2 = EXP2F(sc[sl * 2][qtile][2]),     a3 = EXP2F(sc[sl * 2][qtile][3]);
        float b0 = EXP2F(sc[sl * 2 + 1][qtile][0]), b1 = EXP2F(sc[sl * 2 + 1][qtile][1]);
        float b2 = EXP2F(sc[sl * 2 + 1][qtile][2]), b3 = EXP2F(sc[sl * 2 + 1][qtile][3]);
        pu.u[0] = pk2bf_fast(a0, a1);
        pu.u[1] = pk2bf_fast(a2, a3);
        pu.u[2] = pk2bf_fast(b0, b1);
        pu.u[3] = pk2bf_fast(b2, b3);
        pf[sl][qtile] = pu.s;
      }

    // O^T += V^T · P ; l += 1 · P
#pragma unroll
    for (int sl = 0; sl < 2; ++sl) {
      short8 vf[4];
#pragma unroll
      for (int dtile = 0; dtile < 4; ++dtile)
        vf[dtile] = *(const short8*)(Vts + (dtile * 16 + l15) * 64 + ((((sl * 4 + lg) << 3)) ^ sw));
#pragma unroll
      for (int dtile = 0; dtile < 4; ++dtile)
#pragma unroll
        for (int qtile = 0; qtile < 2; ++qtile)
          acc[dtile][qtile] = __builtin_amdgcn_mfma_f32_16x16x32_bf16(vf[dtile], pf[sl][qtile], acc[dtile][qtile], 0, 0, 0);
#pragma unroll
      for (int qtile = 0; qtile < 2; ++qtile)
        accl[qtile] = __builtin_amdgcn_mfma_f32_16x16x32_bf16(ones8, pf[sl][qtile], accl[qtile], 0, 0, 0);
    }
  }

  // epilogue: normalize (lane owns q = l15 per qtile), transpose O^T -> O via
  // SP (wave-private strips, same-wave in-order), then coalesced swizzled
  // stores to ctx[b, s, h*64+d].
#pragma unroll
  for (int qtile = 0; qtile < 2; ++qtile) {
    float inv = 1.0f / accl[qtile][0];
#pragma unroll
    for (int dtile = 0; dtile < 4; ++dtile) {
      ushort4v pk;
#pragma unroll
      for (int r = 0; r < 4; ++r)
        pk[r] = f2bf(acc[dtile][qtile][r] * inv);   // d = dtile*16 + lg*4 + r
      *(ushort4v*)(SP + (row0 + qtile * 16 + l15) * 72 + dtile * 16 + lg * 4) = pk;
    }
  }
#pragma unroll
  for (int i = 0; i < 4; ++i) {
    int idx = i * 64 + lane;               // 256 chunks = 32 rows x 8
    int rl = idx >> 3, c = idx & 7;
    short8 vv = *(const short8*)(SP + (row0 + rl) * 72 + c * 8);
    int s = qt * 128 + row0 + rl;
    int cs = c ^ (s & 7);                  // chunk swizzle by s&7 for gemm_out
    *(short8*)(ctxg + ((long)b * 2048 + s) * 1024 + h * 64 + cs * 8) = vv;
  }
}

// ------------------------------------------------------------ out projection
// out[m,n] = sum_k ctx[m,k]*Wo[n,k] + bo[n], fp32 out. 64x64 tiles, grid
// (16,64) = 1024 blocks, 32 KB LDS -> 4 blocks/CU (16 waves).
__global__ __launch_bounds__(256) void gemm_out(
    const u16* __restrict__ cb, const u16* __restrict__ wob,
    const float* __restrict__ bo, float* __restrict__ out) {
  __shared__ u16 smem[16384];  // As[2][4096] | Bs[2][4096] = 32 KB
  u16* As = smem;
  u16* Bs = smem + 8192;
  const int tid = threadIdx.x, lane = tid & 63;
  const int wid = tid >> 6;
  const int l15 = lane & 15, lg = lane >> 4;
  const int m0 = blockIdx.y * 64, n0 = blockIdx.x * 64;
  const int sw = ((l15 & 7) << 3);

  f32x4 acc[4] = {};

#pragma unroll
  for (int i = 0; i < 2; ++i) {
    int c = i * 256 + tid;
    gl2lds16(cb  + (m0 + (c >> 3)) * 1024 + (c & 7) * 8, As + c * 8);
    gl2lds16(wob + (n0 + (c >> 3)) * 1024 + (c & 7) * 8, Bs + c * 8);
  }

  for (int k0 = 0; k0 < 1024; k0 += 64) {
    const int p = (k0 >> 6) & 1;
    __syncthreads();
    if (k0 < 960) {
      u16* An = As + (1 - p) * 4096;
      u16* Bn = Bs + (1 - p) * 4096;
#pragma unroll
      for (int i = 0; i < 2; ++i) {
        int c = i * 256 + tid;
        gl2lds16(cb  + (m0 + (c >> 3)) * 1024 + k0 + 64 + (c & 7) * 8, An + c * 8);
        gl2lds16(wob + (n0 + (c >> 3)) * 1024 + k0 + 64 + (c & 7) * 8, Bn + c * 8);
      }
    }
    const u16* Ap = As + p * 4096;
    const u16* Bp = Bs + p * 4096;
#pragma unroll
    for (int kk = 0; kk < 2; ++kk) {
      short8 af, bf[4];
      af = *(const short8*)(Ap + (wid * 16 + l15) * 64 + ((((kk * 4 + lg) << 3)) ^ sw));
#pragma unroll
      for (int nb = 0; nb < 4; ++nb)
        bf[nb] = *(const short8*)(Bp + (nb * 16 + l15) * 64 + ((((kk * 4 + lg) << 3)) ^ sw));
#pragma unroll
      for (int nb = 0; nb < 4; ++nb)
        acc[nb] = __builtin_amdgcn_mfma_f32_16x16x32_bf16(af, bf[nb], acc[nb], 0, 0, 0);
    }
  }

#pragma unroll
  for (int nb = 0; nb < 4; ++nb)
#pragma unroll
    for (int r = 0; r < 4; ++r) {
      int m = m0 + wid * 16 + lg * 4 + r;
      int n = n0 + nb * 16 + l15;
      out[m * 1024 + n] = acc[nb][r] + bo[n];
    }
}

// --------------------------------------------------------------------- launch
extern "C" void kernel_launch(void* const* d_in, const int* in_sizes, int n_in,
                              void* d_out, int out_size, void* d_ws, size_t ws_size,
                              hipStream_t stream) {
  const float* x  = (const float*)d_in[0];
  const float* wq = (const float*)d_in[1];
  const float* bq = (const float*)d_in[2];
  const float* wk = (const float*)d_in[3];
  const float* bk = (const float*)d_in[4];
  const float* wv = (const float*)d_in[5];
  const float* bv = (const float*)d_in[6];
  const float* wo = (const float*)d_in[7];
  const float* bo = (const float*)d_in[8];

  if (ws_size < (size_t)24 * 1024 * 1024 * 2) return;
  u16* xb   = (u16*)d_ws;              // chunk-swizzled
  u16* wqb  = xb  + (4u << 20);        // chunk-swizzled
  u16* wkb  = wqb + (1u << 20);
  u16* wvb  = wkb + (1u << 20);
  u16* wob  = wvb + (1u << 20);
  u16* qb   = wob + (1u << 20);        // plain [B,NH,S,D], pre-scaled
  u16* kb   = qb  + (4u << 20);        // chunk-swizzled [B,NH,S,D]
  u16* vtb  = kb  + (4u << 20);        // V^T [B,NH,D,Sperm], chunk-swizzled
  u16* ctxb = vtb + (4u << 20);        // chunk-swizzled [B,S,H]

  cvt_kernel<<<dim3(512, 8, 1), 256, 0, stream>>>(x, wq, wk, wv, wo, xb, wqb, wkb, wvb, wob);
  gemm_qkv<<<dim3(16, 32, 1), 256, 0, stream>>>(xb, wqb, wkb, wvb, bq, bk, bv, qb, kb, vtb);
  attn_kernel<<<dim3(16, 16, 2), 256, 0, stream>>>(qb, kb, vtb, ctxb);
  gemm_out<<<dim3(16, 64, 1), 256, 0, stream>>>(ctxb, wob, bo, (float*)d_out);
}